// Round 11
// baseline (203.126 us; speedup 1.0000x reference)
//
#include <hip/hip_runtime.h>
#include <hip/hip_bf16.h>

// MultiHeadSelfAttention: B=2, S=2048, D=1024, H=16, DK=64
// R11: attn rewritten as register-direct (no LDS, no barriers in k-loop):
//   each wave loads its K/V fragments straight from global (coalesced; the
//   2 waves/block share the 16KB tile through L1), mask via int4 loads,
//   register A/B double-buffer so the compiler pipelines with vmcnt(N).
//   R10's barrier structure stalled ~3300 cyc/iter on the vmcnt(0) drain at
//   1 wave/SIMD. GEMM/prep path unchanged from R10.

using bf16 = __hip_bfloat16;
typedef __attribute__((ext_vector_type(8))) short bf16x8;   // 8 bf16 = 4 VGPRs
typedef __attribute__((ext_vector_type(4))) float f32x4;

#define QSCALE 0.18033688011112042f   // (1/sqrt(64)) * log2(e)

static __device__ __forceinline__ f32x4 mfma_bf16(bf16x8 a, bf16x8 b, f32x4 c) {
    return __builtin_amdgcn_mfma_f32_16x16x32_bf16(a, b, c, 0, 0, 0);
}

static __device__ __forceinline__ void gld_lds16(const void* g, void* s) {
    __builtin_amdgcn_global_load_lds(
        (const __attribute__((address_space(1))) unsigned int*)g,
        (__attribute__((address_space(3))) unsigned int*)s,
        16, 0, 0);
}

// pack two fp32 -> bf16x2 (round-half-up), 3 VALU ops
static __device__ __forceinline__ unsigned int pk_bf16(float lo, float hi) {
    unsigned int ul = __builtin_bit_cast(unsigned int, lo) + 0x8000u;
    unsigned int uh = __builtin_bit_cast(unsigned int, hi) + 0x8000u;
    return __builtin_amdgcn_perm(uh, ul, 0x07060302u);   // {ul.hi16, uh.hi16}
}

// ---------------- fused prep: cast x + transpose both weights ----------------
// wqkvT row' = which*1024 + h*64 + dk (QSCALE folded into which==0 rows)
__global__ void prep_kernel(const float* __restrict__ x, bf16* __restrict__ xb,
                            const float* __restrict__ wqkv, bf16* __restrict__ wqkvT,
                            const float* __restrict__ wo, bf16* __restrict__ woT) {
    __shared__ float tile[32][33];
    int blk = blockIdx.x;
    if (blk < 4096) {
        int i = blk * 256 + threadIdx.x;
        float4 f = reinterpret_cast<const float4*>(x)[i];
        xb[4*i+0] = __float2bfloat16(f.x);
        xb[4*i+1] = __float2bfloat16(f.y);
        xb[4*i+2] = __float2bfloat16(f.z);
        xb[4*i+3] = __float2bfloat16(f.w);
        return;
    }
    int xo = threadIdx.x & 31, yo = threadIdx.x >> 5;   // (32,8)
    if (blk < 7168) {
        int idx = blk - 4096;
        int c0 = (idx % 96) * 32, r0 = (idx / 96) * 32;
#pragma unroll
        for (int i = 0; i < 32; i += 8)
            tile[yo + i][xo] = wqkv[(size_t)(r0 + yo + i) * 3072 + c0 + xo];
        __syncthreads();
#pragma unroll
        for (int i = 0; i < 32; i += 8) {
            int c = c0 + yo + i;
            int hh = c / 192, rem = c - hh * 192;
            int which = rem >> 6, dk = rem & 63;
            int rowp = which * 1024 + hh * 64 + dk;
            float sc = (which == 0) ? QSCALE : 1.0f;
            wqkvT[(size_t)rowp * 1024 + r0 + xo] = __float2bfloat16(tile[xo][yo + i] * sc);
        }
    } else {
        int idx = blk - 7168;
        int c0 = (idx & 31) * 32, r0 = (idx >> 5) * 32;
#pragma unroll
        for (int i = 0; i < 32; i += 8)
            tile[yo + i][xo] = wo[(size_t)(r0 + yo + i) * 1024 + c0 + xo];
        __syncthreads();
#pragma unroll
        for (int i = 0; i < 32; i += 8)
            woT[(size_t)(c0 + yo + i) * 1024 + r0 + xo] = __float2bfloat16(tile[xo][yo + i]);
    }
}

// ---------------- GEMM: C[M,N] = A[M,K] @ Bt[N,K]^T  (bf16 in, fp32 acc) ----------------
template <int EPI, int TM, int MINW>
__global__ __launch_bounds__(256, MINW)
void gemm_bt_kernel(const bf16* __restrict__ A, const bf16* __restrict__ Bt,
                    int M, int N, int K,
                    const float* __restrict__ bias, const float* __restrict__ gamma,
                    bf16* __restrict__ Qout, bf16* __restrict__ Kout, bf16* __restrict__ Vout,
                    float* __restrict__ Cout) {
    constexpr int MI = TM / 32;
    constexpr int CA = TM / 32;
    __shared__ __align__(16) bf16 smem[TM * 64 + 128 * 64];
    bf16* As = smem;
    bf16* Bs = smem + TM * 64;

    const int tid  = threadIdx.x;
    const int wave = tid >> 6, lane = tid & 63;
    const int quad = lane >> 4, l16 = lane & 15;
    const int wr = wave >> 1, wc = wave & 1;
    const int bm = blockIdx.y, bn = blockIdx.x;

    f32x4 acc[MI][4] = {};

    const int crow = lane >> 3;
    const int sblk = (lane & 7) ^ (crow & 7);
    const bf16* gA[CA]; const bf16* gB[4]; bf16* lA[CA]; bf16* lB[4];
#pragma unroll
    for (int c = 0; c < CA; ++c) {
        int ch = wave * CA + c;
        gA[c] = A + (size_t)(bm * TM + ch * 8 + crow) * K + sblk * 8;
        lA[c] = As + ch * 512 + lane * 8;
    }
#pragma unroll
    for (int c = 0; c < 4; ++c) {
        int ch = wave * 4 + c;
        gB[c] = Bt + (size_t)(bn * 128 + ch * 8 + crow) * K + sblk * 8;
        lB[c] = Bs + ch * 512 + lane * 8;
    }
    const int xr = l16 & 7;

    for (int k0 = 0; k0 < K; k0 += 64) {
#pragma unroll
        for (int c = 0; c < CA; ++c) gld_lds16(gA[c] + k0, lA[c]);
#pragma unroll
        for (int c = 0; c < 4; ++c) gld_lds16(gB[c] + k0, lB[c]);
        __syncthreads();
#pragma unroll
        for (int ks = 0; ks < 2; ++ks) {
            bf16x8 af[MI], bfr[4];
#pragma unroll
            for (int mi = 0; mi < MI; ++mi)
                af[mi] = *(const bf16x8*)(As + (wr * (TM/2) + mi * 16 + l16) * 64 + ((4 * ks + quad) ^ xr) * 8);
#pragma unroll
            for (int ni = 0; ni < 4; ++ni)
                bfr[ni] = *(const bf16x8*)(Bs + (wc * 64 + ni * 16 + l16) * 64 + ((4 * ks + quad) ^ xr) * 8);
#pragma unroll
            for (int mi = 0; mi < MI; ++mi)
#pragma unroll
                for (int ni = 0; ni < 4; ++ni)
                    acc[mi][ni] = mfma_bf16(af[mi], bfr[ni], acc[mi][ni]);
        }
        __syncthreads();
    }

    if (EPI == 0 && bn >= 16) {
        // ---- V path: in-LDS transpose + permuted coalesced V^T store ----
        __syncthreads();
        uint2* Tu = (uint2*)smem;   // 128 cols x 32 row-groups of 8B, XOR-swizzled
#pragma unroll
        for (int mi = 0; mi < MI; ++mi) {
#pragma unroll
            for (int ni = 0; ni < 4; ++ni) {
                int colL = wc * 64 + ni * 16 + l16;
                float bv = bias[(2 * (bn - 16) + wc) * 192 + 128 + (ni * 16 + l16)];
                uint2 pk;
                pk.x = pk_bf16(acc[mi][ni][0] + bv, acc[mi][ni][1] + bv);
                pk.y = pk_bf16(acc[mi][ni][2] + bv, acc[mi][ni][3] + bv);
                int rg = wr * 16 + mi * 4 + quad;
                Tu[colL * 32 + (rg ^ (colL & 31))] = pk;
            }
        }
        __syncthreads();
        const int sub = tid & 15, rbase = tid >> 4;
        const int cs = sub >> 3, aa = (sub >> 2) & 1, qq = sub & 3;
        const int g1 = cs * 16 + aa * 8 + qq;
        const int g2 = g1 + 4;
        const int b = bm >> 4;
        const int s0 = (bm & 15) * 128;
#pragma unroll
        for (int j = 0; j < 8; ++j) {
            int rt = rbase + 16 * j;
            int hh = 2 * (bn - 16) + (rt >> 6), dk = rt & 63;
            uint2 lo = Tu[rt * 32 + (g1 ^ (rt & 31))];
            uint2 hi = Tu[rt * 32 + (g2 ^ (rt & 31))];
            uint4 val; val.x = lo.x; val.y = lo.y; val.z = hi.x; val.w = hi.y;
            *(uint4*)(Vout + (((size_t)b * 16 + hh) * 64 + dk) * 2048 + s0 + sub * 8) = val;
        }
        return;
    }

#pragma unroll
    for (int mi = 0; mi < MI; ++mi) {
#pragma unroll
        for (int ni = 0; ni < 4; ++ni) {
            int col = bn * 128 + wc * 64 + ni * 16 + l16;
            if (EPI == 0) {
                int which = col >> 10, hh = (col >> 6) & 15, dk = col & 63;
                float bv = bias[hh * 192 + which * 64 + dk];
                if (which == 0) bv *= QSCALE;
                bf16* dst = which ? Kout : Qout;
#pragma unroll
                for (int r = 0; r < 4; ++r) {
                    int row = bm * TM + wr * (TM/2) + mi * 16 + quad * 4 + r;
                    int b = row >> 11, s = row & 2047;   // S = 2048
                    dst[(((size_t)b * 16 + hh) * 2048 + s) * 64 + dk] =
                        __float2bfloat16(acc[mi][ni][r] + bv);
                }
            } else {
                float g1 = gamma[col] + 1.0f, bv = bias[col];
#pragma unroll
                for (int r = 0; r < 4; ++r) {
                    int row = bm * TM + wr * (TM/2) + mi * 16 + quad * 4 + r;
                    Cout[(size_t)row * N + col] = g1 * (acc[mi][ni][r] + bv);
                }
            }
        }
    }
}

// ---------------- flash attention: register-direct, no LDS, no barriers ----------------
// grid (S/128, B*H), block 128. Wave w owns q rows [q0+64w, +64) as m=0..3.
// S^T = K*Q^T orientation; V^T pre-permuted (dual-slice) so each PV B-frag is
// one contiguous 16B global read. Register A/B double-buffer over k-tiles.
__global__ __launch_bounds__(128, 1)
void attn_kernel(const bf16* __restrict__ Qb, const bf16* __restrict__ Kb,
                 const bf16* __restrict__ Vtp, const int* __restrict__ mask,
                 bf16* __restrict__ Aout) {
    const int bh = blockIdx.y;
    const int b = bh >> 4, h = bh & 15;
    const int q0 = blockIdx.x * 128;
    const int tid = threadIdx.x;
    const int wave = tid >> 6, lane = tid & 63;
    const int quad = lane >> 4, l16 = lane & 15;

    // Q fragments (B-operand of the S^T MFMA)
    bf16x8 aq[4][2];
#pragma unroll
    for (int m = 0; m < 4; ++m) {
        const bf16* qp = Qb + ((size_t)bh * 2048 + q0 + wave * 64 + m * 16 + l16) * 64;
        aq[m][0] = *(const bf16x8*)(qp + quad * 8);
        aq[m][1] = *(const bf16x8*)(qp + 32 + quad * 8);
    }

    bf16x8 ones;
#pragma unroll
    for (int j = 0; j < 8; ++j) ones[j] = (short)0x3F80;   // bf16 1.0

    f32x4 O[4][4] = {};
    f32x4 Lacc[4] = {};

    // per-lane fragment base addresses
    const bf16* kbase = Kb  + ((size_t)bh * 2048 + l16) * 64 + quad * 8;
    const bf16* vbase = Vtp + ((size_t)bh * 64 + l16) * 2048 + quad * 8;
    const int*  mbase = mask + b * 2048 + quad * 4;

    bf16x8 bkA[4][2], bvA[2][4]; int4 mA[4];
    bf16x8 bkB[4][2], bvB[2][4]; int4 mB[4];

    auto loadT = [&](int kt, bf16x8 bk[4][2], bf16x8 bv[2][4], int4 mq[4]) {
#pragma unroll
        for (int kt4 = 0; kt4 < 4; ++kt4) {
            const bf16* p = kbase + (size_t)(kt * 64 + kt4 * 16) * 64;
            bk[kt4][0] = *(const bf16x8*)p;
            bk[kt4][1] = *(const bf16x8*)(p + 32);
            mq[kt4] = *(const int4*)(mbase + kt * 64 + kt4 * 16);
        }
#pragma unroll
        for (int a = 0; a < 2; ++a)
#pragma unroll
            for (int nt = 0; nt < 4; ++nt)
                bv[a][nt] = *(const bf16x8*)(vbase + (size_t)nt * 32768 + kt * 64 + a * 32);
    };

    auto step = [&](bf16x8 bk[4][2], bf16x8 bv[2][4], int4 mq[4]) {
        f32x4 bias4[4];
#pragma unroll
        for (int kt4 = 0; kt4 < 4; ++kt4) {
            bias4[kt4][0] = mq[kt4].x ? -24.0f : -1e30f;
            bias4[kt4][1] = mq[kt4].y ? -24.0f : -1e30f;
            bias4[kt4][2] = mq[kt4].z ? -24.0f : -1e30f;
            bias4[kt4][3] = mq[kt4].w ? -24.0f : -1e30f;
        }
#pragma unroll
        for (int m = 0; m < 4; ++m) {
            f32x4 sv[4];
#pragma unroll
            for (int kt4 = 0; kt4 < 4; ++kt4) {
                f32x4 c = {0.f, 0.f, 0.f, 0.f};
                c = mfma_bf16(bk[kt4][0], aq[m][0], c);
                c = mfma_bf16(bk[kt4][1], aq[m][1], c);
                sv[kt4] = c;
            }
            float p[4][4];
#pragma unroll
            for (int kt4 = 0; kt4 < 4; ++kt4)
#pragma unroll
                for (int r = 0; r < 4; ++r)
                    p[kt4][r] = __builtin_amdgcn_exp2f(sv[kt4][r] + bias4[kt4][r]);

#pragma unroll
            for (int a = 0; a < 2; ++a) {
                uint4 uv;
                uv.x = pk_bf16(p[2*a][0],   p[2*a][1]);
                uv.y = pk_bf16(p[2*a][2],   p[2*a][3]);
                uv.z = pk_bf16(p[2*a+1][0], p[2*a+1][1]);
                uv.w = pk_bf16(p[2*a+1][2], p[2*a+1][3]);
                bf16x8 pa = __builtin_bit_cast(bf16x8, uv);
                Lacc[m] = mfma_bf16(pa, ones, Lacc[m]);
#pragma unroll
                for (int nt = 0; nt < 4; ++nt)
                    O[m][nt] = mfma_bf16(pa, bv[a][nt], O[m][nt]);
            }
        }
    };

    loadT(0, bkA, bvA, mA);
    for (int kt = 0; kt < 32; kt += 2) {
        loadT(kt + 1, bkB, bvB, mB);          // prefetch while computing A
        step(bkA, bvA, mA);
        int n2 = (kt + 2 < 32) ? kt + 2 : 0;  // clamp (dummy load on last)
        loadT(n2, bkA, bvA, mA);
        step(bkB, bvB, mB);
    }

    // epilogue: O / l
#pragma unroll
    for (int m = 0; m < 4; ++m) {
        float inv[4];
#pragma unroll
        for (int r = 0; r < 4; ++r) inv[r] = __builtin_amdgcn_rcpf(Lacc[m][r]);
#pragma unroll
        for (int nt = 0; nt < 4; ++nt) {
#pragma unroll
            for (int r = 0; r < 4; ++r) {
                int row = q0 + wave * 64 + m * 16 + quad * 4 + r;
                Aout[((size_t)b * 2048 + row) * 1024 + h * 64 + nt * 16 + l16] =
                    __float2bfloat16(O[m][nt][r] * inv[r]);
            }
        }
    }
}

// ---------------- launcher ----------------
extern "C" void kernel_launch(void* const* d_in, const int* in_sizes, int n_in,
                              void* d_out, int out_size, void* d_ws, size_t ws_size,
                              hipStream_t stream) {
    const float* x     = (const float*)d_in[0];
    const float* gamma = (const float*)d_in[1];
    const int*   mask  = (const int*)d_in[2];
    const float* wqkv  = (const float*)d_in[3];
    const float* bqkv  = (const float*)d_in[4];
    const float* wo    = (const float*)d_in[5];
    const float* bo    = (const float*)d_in[6];
    float* out = (float*)d_out;

    char* ws = (char*)d_ws;
    const size_t MB = 1u << 20;
    bf16* xb    = (bf16*)(ws);            //  8 MB
    bf16* wqkvT = (bf16*)(ws + 8 * MB);   //  6 MB (which-major, QSCALE folded)
    bf16* woT   = (bf16*)(ws + 14 * MB);  //  2 MB
    bf16* Qb    = (bf16*)(ws + 16 * MB);  //  8 MB
    bf16* Kb    = (bf16*)(ws + 24 * MB);  //  8 MB
    bf16* Vt    = (bf16*)(ws + 32 * MB);  //  8 MB (V^T, kpos-permuted; written by GEMM)
    bf16* attn  = (bf16*)(ws + 40 * MB);  //  8 MB

    prep_kernel<<<8192, 256, 0, stream>>>(x, xb, wqkv, wqkvT, wo, woT);

    // QKV GEMM: [4096,1024] x [1024,3072]; V blocks write Vt directly
    gemm_bt_kernel<0, 128, 3><<<dim3(24, 32), 256, 0, stream>>>(
        xb, wqkvT, 4096, 3072, 1024, bqkv, nullptr, Qb, Kb, Vt, nullptr);

    // attention: grid (S/128, B*H), 128-thread blocks, register-direct
    attn_kernel<<<dim3(16, 32), 128, 0, stream>>>(Qb, Kb, Vt, mask, attn);

    // out GEMM: [4096,1024] x [1024,1024]
    gemm_bt_kernel<1, 64, 4><<<dim3(8, 64), 256, 0, stream>>>(
        attn, woT, 4096, 1024, 1024, bo, gamma, nullptr, nullptr, nullptr, out);
}